// Round 3
// baseline (354.337 us; speedup 1.0000x reference)
//
#include <hip/hip_runtime.h>
#include <hip/hip_bf16.h>

#define NBANDS 5
#define BATCH  16
#define DIM    256
#define NNODE  64
#define SEQ    5
#define NHEAD  4
#define DHEAD  64

typedef __hip_bfloat16 bf16;

__device__ __forceinline__ float bu2f(unsigned short u){
    bf16 h = *reinterpret_cast<bf16*>(&u);
    return __bfloat162float(h);
}
__device__ __forceinline__ unsigned short f2bu(float x){
    bf16 h = __float2bfloat16(x);
    return *reinterpret_cast<unsigned short*>(&h);
}

// ---------------- per-band static bases: softmax(adj_w)+pf*softmax(pos_enc) ----
__global__ void k_bases(const float* __restrict__ l_adj_w, const float* __restrict__ l_pos_enc,
                        const float* __restrict__ l_pf,
                        const float* __restrict__ g_adj_w, const float* __restrict__ g_pos_enc,
                        const float* __restrict__ g_pf,
                        float* __restrict__ sbase, float* __restrict__ gbase)
{
    int blk = blockIdx.x;
    int t = threadIdx.x;
    if (blk < NBANDS*NNODE) {
        int k = blk / NNODE, i = blk % NNODE;
        float aw = l_adj_w[(k*NNODE + i)*NNODE + t];
        float pe = l_pos_enc[(k*NNODE + i)*NNODE + t];
        float m1 = aw, m2 = pe;
        for (int o=32;o>0;o>>=1){ m1 = fmaxf(m1, __shfl_xor(m1,o,64)); m2 = fmaxf(m2, __shfl_xor(m2,o,64)); }
        float e1 = __expf(aw-m1), e2 = __expf(pe-m2);
        float s1=e1, s2=e2;
        for (int o=32;o>0;o>>=1){ s1 += __shfl_xor(s1,o,64); s2 += __shfl_xor(s2,o,64); }
        float pf = l_pf[k];
        sbase[(k*NNODE+i)*NNODE + t] = e1/s1 + pf*(e2/s2);
    } else if (t < NBANDS) {
        int i = t;
        float r1[NBANDS], r2[NBANDS];
        float m1=-1e30f, m2=-1e30f;
        for (int j=0;j<NBANDS;j++){
            r1[j]=g_adj_w[i*NBANDS+j]; r2[j]=g_pos_enc[i*NBANDS+j];
            m1=fmaxf(m1,r1[j]); m2=fmaxf(m2,r2[j]);
        }
        float s1=0.f,s2=0.f;
        for (int j=0;j<NBANDS;j++){ r1[j]=__expf(r1[j]-m1); r2[j]=__expf(r2[j]-m2); s1+=r1[j]; s2+=r2[j]; }
        float pf = g_pf[0];
        for (int j=0;j<NBANDS;j++) gbase[i*NBANDS+j] = r1[j]/s1 + pf*(r2[j]/s2);
    }
}

// ---------------- feature f32 [B,5*D,1,N] -> xtb bf16 [k,b,n,d] -------------
__global__ void k_transpose_feat(const float* __restrict__ feat,
                                 unsigned short* __restrict__ xtb)
{
    int k = blockIdx.x / BATCH, b = blockIdx.x % BATCH;
    __shared__ unsigned short tile[64][65];
    const float* src = feat + ((size_t)b*NBANDS*DIM + (size_t)k*DIM)*NNODE; // [D][N]
    unsigned short* dst = xtb + (size_t)(k*BATCH+b)*NNODE*DIM;              // [N][D]
    int tid = threadIdx.x;
    for (int dt=0; dt<4; ++dt){
        for (int r=0;r<16;r++){
            int dp = r*4 + (tid>>6);
            int n  = tid & 63;
            tile[dp][n] = f2bu(src[(size_t)(dt*64+dp)*NNODE + n]);
        }
        __syncthreads();
        for (int r=0;r<16;r++){
            int n  = r*4 + (tid>>6);
            int dp = tid & 63;
            dst[(size_t)n*DIM + dt*64 + dp] = tile[dp][n];
        }
        __syncthreads();
    }
}

// ---------------- a = xt@W1[:D]+b1, bp = xt@W1[D:], 8 rows/block (bf16 out) --
__global__ void k_ab(const unsigned short* __restrict__ xtb, const float* __restrict__ w1,
                     const float* __restrict__ b1,
                     unsigned short* __restrict__ aab, unsigned short* __restrict__ bbb)
{
    int blk = blockIdx.x;
    int k = blk / (BATCH*8);
    int b = (blk / 8) % BATCH;
    int i0 = (blk % 8) * 8;
    int kb = k*BATCH + b;
    __shared__ float xr[8][DIM];
    int tid = threadIdx.x;
    for (int r=0;r<8;r++) xr[r][tid] = bu2f(xtb[((size_t)kb*NNODE + i0 + r)*DIM + tid]);
    __syncthreads();
    const float* W = w1 + (size_t)k*2*DIM*DIM;
    float accA[8], accB[8];
    #pragma unroll
    for (int r=0;r<8;r++){ accA[r]=0.f; accB[r]=0.f; }
    for (int dp=0; dp<DIM; ++dp){
        float wa = W[(size_t)dp*DIM + tid];
        float wb = W[(size_t)(DIM+dp)*DIM + tid];
        #pragma unroll
        for (int r=0;r<8;r++){
            float xv = xr[r][dp];
            accA[r] += xv*wa;
            accB[r] += xv*wb;
        }
    }
    float bias = b1[k*DIM + tid];
    for (int r=0;r<8;r++){
        size_t idx = ((size_t)kb*NNODE + i0 + r)*DIM + tid;
        aab[idx] = f2bu(accA[r] + bias);
        bbb[idx] = f2bu(accB[r]);
    }
}

// ------- dyn = sigmoid(sum_d elu(a_i+bp_j)*w2 + b2); comb = softmax row -----
__global__ void k_dyn_comb(const unsigned short* __restrict__ aab,
                           const unsigned short* __restrict__ bbb,
                           const float* __restrict__ w2, const float* __restrict__ b2arr,
                           const float* __restrict__ sbase,
                           float* __restrict__ comb)
{
    int blk = blockIdx.x;                     // NBANDS*BATCH*16 blocks, 4 i-rows each
    int k = blk / (BATCH*16);
    int b = (blk / 16) % BATCH;
    int i0 = (blk % 16) * 4;
    int kb = k*BATCH + b;
    __shared__ float arows[4][DIM];
    __shared__ float w2s[DIM];
    __shared__ float dyn_s[4][NNODE];
    int tid = threadIdx.x;
    int wave = tid >> 6, lane = tid & 63;
    for (int r=0;r<4;r++) arows[r][tid] = bu2f(aab[((size_t)kb*NNODE + i0 + r)*DIM + tid]);
    w2s[tid] = w2[k*DIM + tid];
    __syncthreads();
    const unsigned short* bpbase = bbb + (size_t)kb*NNODE*DIM;
    for (int jt=0; jt<16; ++jt){
        int j = jt*4 + wave;
        const unsigned short* bj = bpbase + (size_t)j*DIM;
        float acc[4] = {0.f,0.f,0.f,0.f};
        #pragma unroll
        for (int m=0;m<4;m++){
            int dd = lane + m*64;
            float bpv = bu2f(bj[dd]);
            float wv  = w2s[dd];
            #pragma unroll
            for (int r=0;r<4;r++){
                float v = arows[r][dd] + bpv;
                float e = (v > 0.f) ? v : (__expf(v) - 1.f);   // elu
                acc[r] += e*wv;
            }
        }
        #pragma unroll
        for (int r=0;r<4;r++){
            float s = acc[r];
            for (int o=32;o>0;o>>=1) s += __shfl_xor(s,o,64);
            if (lane==0) dyn_s[r][j] = s;
        }
    }
    __syncthreads();
    // softmax per row: wave r handles row i0+r over its 64 lanes
    {
        float sb2 = b2arr[k];
        float t = dyn_s[wave][lane] + sb2;
        float sg = 1.f/(1.f + __expf(-t));
        float val = sbase[(k*NNODE + i0 + wave)*NNODE + lane] + sg;
        float m = val;
        for (int o=32;o>0;o>>=1) m = fmaxf(m, __shfl_xor(m,o,64));
        float e = __expf(val - m);
        float s = e;
        for (int o=32;o>0;o>>=1) s += __shfl_xor(s,o,64);
        comb[((size_t)kb*NNODE + i0 + wave)*NNODE + lane] = e/s;
    }
}

// ---------------- y = comb @ xt, 8 rows/block (bf16 out, reuses aab) --------
__global__ void k_y(const float* __restrict__ comb, const unsigned short* __restrict__ xtb,
                    unsigned short* __restrict__ yb)
{
    int blk = blockIdx.x;
    int k = blk / (BATCH*8);
    int b = (blk / 8) % BATCH;
    int i0 = (blk % 8) * 8;
    int kb = k*BATCH + b;
    __shared__ float cr[8][NNODE];
    int tid = threadIdx.x;
    for (int u=0;u<2;u++){
        int idx = u*256 + tid;
        cr[idx>>6][idx&63] = comb[((size_t)kb*NNODE + i0 + (idx>>6))*NNODE + (idx&63)];
    }
    __syncthreads();
    const unsigned short* xb = xtb + (size_t)kb*NNODE*DIM;
    float acc[8] = {0.f,0.f,0.f,0.f,0.f,0.f,0.f,0.f};
    for (int j=0;j<NNODE;++j){
        float xv = bu2f(xb[(size_t)j*DIM + tid]);
        #pragma unroll
        for (int r=0;r<8;r++) acc[r] += cr[r][j]*xv;
    }
    for (int r=0;r<8;r++) yb[((size_t)kb*NNODE + i0 + r)*DIM + tid] = f2bu(acc[r]);
}

// ---- z = y @ gcn_w + gcn_b; write DIRECTLY to out_local [b,k,d,n] f32 ------
__global__ void k_gcn(const unsigned short* __restrict__ yb, const float* __restrict__ gw,
                      const float* __restrict__ gb,
                      float* __restrict__ out_local)
{
    int blk = blockIdx.x;
    int k = blk / (BATCH*8);
    int b = (blk / 8) % BATCH;
    int i0 = (blk % 8) * 8;
    int kb = k*BATCH + b;
    __shared__ float yr[8][DIM];
    __shared__ float zs[8][DIM];
    int tid = threadIdx.x;
    for (int r=0;r<8;r++) yr[r][tid] = bu2f(yb[((size_t)kb*NNODE + i0 + r)*DIM + tid]);
    __syncthreads();
    const float* W = gw + (size_t)k*DIM*DIM;
    float acc[8];
    #pragma unroll
    for (int r=0;r<8;r++) acc[r]=0.f;
    for (int dp=0;dp<DIM;++dp){
        float wv = W[(size_t)dp*DIM + tid];
        #pragma unroll
        for (int r=0;r<8;r++) acc[r] += yr[r][dp]*wv;
    }
    float bias = gb[k*DIM + tid];
    for (int r=0;r<8;r++) zs[r][tid] = acc[r] + bias;
    __syncthreads();
    // transposed write: thread tid owns d=tid, nodes i0..i0+7 (two 16B stores)
    float4 p0 = make_float4(zs[0][tid], zs[1][tid], zs[2][tid], zs[3][tid]);
    float4 p1 = make_float4(zs[4][tid], zs[5][tid], zs[6][tid], zs[7][tid]);
    float* dst = out_local + ((size_t)(b*NBANDS + k)*DIM + tid)*NNODE + i0;
    reinterpret_cast<float4*>(dst)[0] = p0;
    reinterpret_cast<float4*>(dst)[1] = p1;
}

// ---------------- scale_nodes[b,k,d] = mean_n local_out[b,k,d,n] ------------
__global__ void k_scale(const float* __restrict__ out_local, float* __restrict__ scalew)
{
    int k = blockIdx.x / BATCH, b = blockIdx.x % BATCH;
    int d = threadIdx.x;
    const float* zl = out_local + ((size_t)(b*NBANDS + k)*DIM + d)*NNODE;
    float acc = 0.f;
    for (int n=0;n<NNODE;++n) acc += zl[n];
    scalew[((size_t)b*SEQ + k)*DIM + d] = acc * (1.f/64.f);
}

// ---------------- qkv = scale @ qkv_w + qkv_b -------------------------------
__global__ void k_qkv(const float* __restrict__ scalew, const float* __restrict__ qkv_w,
                      const float* __restrict__ qkv_b,
                      float* __restrict__ qkvw)
{
    int b = blockIdx.x / SEQ, s = blockIdx.x % SEQ;
    __shared__ float xrow[DIM];
    int d = threadIdx.x;
    xrow[d] = scalew[((size_t)b*SEQ + s)*DIM + d];
    __syncthreads();
    float a0=0.f, a1=0.f, a2=0.f;
    for (int dp=0;dp<DIM;++dp){
        float xv = xrow[dp];
        a0 += xv * qkv_w[(size_t)dp*3*DIM + d];
        a1 += xv * qkv_w[(size_t)dp*3*DIM + DIM + d];
        a2 += xv * qkv_w[(size_t)dp*3*DIM + 2*DIM + d];
    }
    size_t o = ((size_t)b*SEQ + s)*3*DIM;
    qkvw[o + d]         = a0 + qkv_b[d];
    qkvw[o + DIM + d]   = a1 + qkv_b[DIM + d];
    qkvw[o + 2*DIM + d] = a2 + qkv_b[2*DIM + d];
}

// ---------------- MHA core: scores, softmax, att@v -> o_ws ------------------
__global__ void k_attn(const float* __restrict__ qkvw, float* __restrict__ ows)
{
    int b = blockIdx.x;
    int tid = threadIdx.x;
    int h = tid >> 6, l = tid & 63;
    __shared__ float att[NHEAD][SEQ][SEQ];
    const float* base = qkvw + (size_t)b*SEQ*3*DIM;
    for (int i=0;i<SEQ;i++){
        float qv = base[(size_t)i*3*DIM + h*DHEAD + l];
        for (int j=0;j<SEQ;j++){
            float kv = base[(size_t)j*3*DIM + DIM + h*DHEAD + l];
            float p = qv * kv;
            for (int o=32;o>0;o>>=1) p += __shfl_xor(p,o,64);
            if (l==0) att[h][i][j] = p * 0.125f;   // / sqrt(64)
        }
    }
    __syncthreads();
    if (l == 0){
        for (int i=0;i<SEQ;i++){
            float m=-1e30f;
            for (int j=0;j<SEQ;j++) m = fmaxf(m, att[h][i][j]);
            float e[SEQ]; float s=0.f;
            for (int j=0;j<SEQ;j++){ e[j] = __expf(att[h][i][j]-m); s+=e[j]; }
            for (int j=0;j<SEQ;j++) att[h][i][j] = e[j]/s;
        }
    }
    __syncthreads();
    for (int i=0;i<SEQ;i++){
        float acc=0.f;
        for (int j=0;j<SEQ;j++) acc += att[h][i][j] * base[(size_t)j*3*DIM + 2*DIM + h*DHEAD + l];
        ows[((size_t)b*SEQ + i)*DIM + h*DHEAD + l] = acc;
    }
}

// ---------------- block LayerNorm over 256 elems ----------------------------
__device__ __forceinline__ float block_ln(float v, int tid, float* red, float g, float bln)
{
    float s = v;
    for (int o=32;o>0;o>>=1) s += __shfl_xor(s,o,64);
    int wave = tid>>6, lane = tid&63;
    if (lane==0) red[wave] = s;
    __syncthreads();
    float mean = (red[0]+red[1]+red[2]+red[3]) * (1.f/DIM);
    float c = v - mean;
    float q = c*c;
    for (int o=32;o>0;o>>=1) q += __shfl_xor(q,o,64);
    __syncthreads();
    if (lane==0) red[wave] = q;
    __syncthreads();
    float var = (red[0]+red[1]+red[2]+red[3]) * (1.f/DIM);
    return c * rsqrtf(var + 1e-5f) * g + bln;
}

// ---------------- proj + residual + LN1 -> h1 -------------------------------
__global__ void k_proj_ln1(const float* __restrict__ ows, const float* __restrict__ ow,
                           const float* __restrict__ ob,
                           const float* __restrict__ scalew,
                           const float* __restrict__ ln1_g, const float* __restrict__ ln1_b,
                           float* __restrict__ h1w)
{
    int b = blockIdx.x / SEQ, s = blockIdx.x % SEQ;
    __shared__ float orow[DIM];
    __shared__ float red[4];
    int d = threadIdx.x;
    orow[d] = ows[((size_t)b*SEQ+s)*DIM + d];
    __syncthreads();
    float acc=0.f;
    for (int dp=0;dp<DIM;++dp) acc += orow[dp] * ow[(size_t)dp*DIM + d];
    float v = acc + ob[d] + scalew[((size_t)b*SEQ+s)*DIM + d];
    float out = block_ln(v, d, red, ln1_g[d], ln1_b[d]);
    h1w[((size_t)b*SEQ+s)*DIM + d] = out;
}

// ---------------- mlp hidden: gelu(h1 @ w1 + b1) ----------------------------
__global__ void k_mlp1(const float* __restrict__ h1w, const float* __restrict__ w1,
                       const float* __restrict__ b1,
                       float* __restrict__ mhw)
{
    int b = blockIdx.x / SEQ, s = blockIdx.x % SEQ;
    __shared__ float xrow[DIM];
    int tid = threadIdx.x;
    xrow[tid] = h1w[((size_t)b*SEQ+s)*DIM + tid];
    __syncthreads();
    for (int c=0;c<4;c++){
        int d = c*256 + tid;
        float acc=0.f;
        for (int dp=0;dp<DIM;++dp) acc += xrow[dp]*w1[(size_t)dp*4*DIM + d];
        acc += b1[d];
        float g = 0.5f*acc*(1.f + erff(acc*0.70710678118654752f));  // exact gelu
        mhw[((size_t)b*SEQ+s)*4*DIM + d] = g;
    }
}

// ---------------- mlp out + residual + LN2 -> se ----------------------------
__global__ void k_mlp2_ln2(const float* __restrict__ mhw, const float* __restrict__ w2,
                           const float* __restrict__ b2v,
                           const float* __restrict__ h1w,
                           const float* __restrict__ ln2_g, const float* __restrict__ ln2_b,
                           float* __restrict__ sew)
{
    int b = blockIdx.x / SEQ, s = blockIdx.x % SEQ;
    __shared__ float xrow[4*DIM];
    __shared__ float red[4];
    int tid = threadIdx.x;
    for (int c=0;c<4;c++) xrow[c*256+tid] = mhw[((size_t)b*SEQ+s)*4*DIM + c*256 + tid];
    __syncthreads();
    float acc=0.f;
    for (int dp=0;dp<4*DIM;++dp) acc += xrow[dp]*w2[(size_t)dp*DIM + tid];
    float v = acc + b2v[tid] + h1w[((size_t)b*SEQ+s)*DIM + tid];
    float out = block_ln(v, tid, red, ln2_g[tid], ln2_b[tid]);
    sew[((size_t)b*SEQ+s)*DIM + tid] = out;
}

// ---------------- global graph: ga = se@gw1[:D]+b1, gbp = se@gw1[D:] --------
__global__ void k_gab(const float* __restrict__ sew, const float* __restrict__ gw1,
                      const float* __restrict__ gb1,
                      float* __restrict__ gaw, float* __restrict__ gbw)
{
    int b = blockIdx.x / SEQ, s = blockIdx.x % SEQ;
    __shared__ float xrow[DIM];
    int d = threadIdx.x;
    xrow[d] = sew[((size_t)b*SEQ+s)*DIM + d];
    __syncthreads();
    float aA=0.f, aB=0.f;
    for (int dp=0;dp<DIM;++dp){
        float xv = xrow[dp];
        aA += xv * gw1[(size_t)dp*DIM + d];
        aB += xv * gw1[(size_t)(DIM+dp)*DIM + d];
    }
    gaw[((size_t)b*SEQ+s)*DIM + d] = aA + gb1[d];
    gbw[((size_t)b*SEQ+s)*DIM + d] = aB;
}

// ---------------- global adj: dyn, comb softmax -> gcomb ws + f32 out -------
__global__ void k_gadj(const float* __restrict__ gaw, const float* __restrict__ gbw,
                       const float* __restrict__ gw2, const float* __restrict__ gb2,
                       const float* __restrict__ gbase,
                       float* __restrict__ gcombw, float* __restrict__ out_gadj)
{
    int b = blockIdx.x;
    int tid = threadIdx.x;
    int wave = tid>>6, lane = tid&63;
    __shared__ float dyn[SEQ][SEQ];
    __shared__ float w2s[DIM];
    w2s[tid] = gw2[tid];
    __syncthreads();
    for (int p = wave; p < SEQ*SEQ; p += 4){
        int i = p / SEQ, j = p % SEQ;
        const float* gar = gaw + ((size_t)b*SEQ+i)*DIM;
        const float* gbr = gbw + ((size_t)b*SEQ+j)*DIM;
        float acc = 0.f;
        #pragma unroll
        for (int m=0;m<4;m++){
            int dd = lane + m*64;
            float v = gar[dd] + gbr[dd];
            float e = (v>0.f) ? v : (__expf(v)-1.f);
            acc += e * w2s[dd];
        }
        for (int o=32;o>0;o>>=1) acc += __shfl_xor(acc,o,64);
        if (lane==0) dyn[i][j] = acc;
    }
    __syncthreads();
    if (tid < SEQ){
        int i = tid;
        float sb2 = gb2[0];
        float row[SEQ]; float m=-1e30f;
        for (int j=0;j<SEQ;j++){
            float sg = 1.f/(1.f+__expf(-(dyn[i][j]+sb2)));
            row[j] = gbase[i*SEQ+j] + sg;
            m = fmaxf(m,row[j]);
        }
        float ssum=0.f;
        for (int j=0;j<SEQ;j++){ row[j]=__expf(row[j]-m); ssum+=row[j]; }
        for (int j=0;j<SEQ;j++){
            float c = row[j]/ssum;
            gcombw[((size_t)b*SEQ+i)*SEQ + j] = c;
            out_gadj[((size_t)b*SEQ+i)*SEQ + j] = c;
        }
    }
}

// ---------------- g_out = (gcomb @ se) @ g_gcn_w + b ------------------------
__global__ void k_gout(const float* __restrict__ gcombw, const float* __restrict__ sew,
                       const float* __restrict__ ggw, const float* __restrict__ ggb,
                       float* __restrict__ goutw)
{
    int b = blockIdx.x / SEQ, k = blockIdx.x % SEQ;
    __shared__ float trow[DIM];
    int tid = threadIdx.x;
    float t = 0.f;
    for (int j=0;j<SEQ;j++) t += gcombw[((size_t)b*SEQ+k)*SEQ + j] * sew[((size_t)b*SEQ+j)*DIM + tid];
    trow[tid] = t;
    __syncthreads();
    float acc = 0.f;
    for (int dp=0;dp<DIM;++dp) acc += trow[dp]*ggw[(size_t)dp*DIM + tid];
    goutw[((size_t)b*SEQ+k)*DIM + tid] = acc + ggb[tid];
}

// ------- final: out0[b,k,d] = gout[b,k,d] * (sum_n local_out*imp_w) + imp_b --
__global__ void k_final(const float* __restrict__ out_local,
                        const float* __restrict__ goutw,
                        const float* __restrict__ imp_w, const float* __restrict__ imp_b,
                        float* __restrict__ out0)
{
    int b = blockIdx.x / NBANDS, k = blockIdx.x % NBANDS;
    __shared__ float iw[NNODE];
    int d = threadIdx.x;
    if (d < NNODE) iw[d] = imp_w[k*NNODE + d];
    __syncthreads();
    const float* zl = out_local + ((size_t)(b*NBANDS + k)*DIM + d)*NNODE;
    float acc = 0.f;
    for (int n=0;n<NNODE;++n) acc += zl[n] * iw[n];
    float val = goutw[((size_t)b*NBANDS+k)*DIM + d] * acc + imp_b[k];
    out0[((size_t)b*NBANDS+k)*DIM + d] = val;
}

extern "C" void kernel_launch(void* const* d_in, const int* in_sizes, int n_in,
                              void* d_out, int out_size, void* d_ws, size_t ws_size,
                              hipStream_t stream)
{
    const float* feature      = (const float*)d_in[0];
    const float* l_adj_w      = (const float*)d_in[1];
    const float* l_sim_w1     = (const float*)d_in[2];
    const float* l_sim_b1     = (const float*)d_in[3];
    const float* l_sim_w2     = (const float*)d_in[4];
    const float* l_sim_b2     = (const float*)d_in[5];
    const float* l_pos_factor = (const float*)d_in[6];
    const float* l_pos_enc    = (const float*)d_in[7];
    const float* l_gcn_w      = (const float*)d_in[8];
    const float* l_gcn_b      = (const float*)d_in[9];
    const float* g_adj_w      = (const float*)d_in[10];
    const float* g_sim_w1     = (const float*)d_in[11];
    const float* g_sim_b1     = (const float*)d_in[12];
    const float* g_sim_w2     = (const float*)d_in[13];
    const float* g_sim_b2     = (const float*)d_in[14];
    const float* g_pos_factor = (const float*)d_in[15];
    const float* g_pos_enc    = (const float*)d_in[16];
    const float* g_gcn_w      = (const float*)d_in[17];
    const float* g_gcn_b      = (const float*)d_in[18];
    const float* qkv_w        = (const float*)d_in[19];
    const float* qkv_b        = (const float*)d_in[20];
    const float* attn_ow      = (const float*)d_in[21];
    const float* attn_ob      = (const float*)d_in[22];
    const float* ln1_g        = (const float*)d_in[23];
    const float* ln1_b        = (const float*)d_in[24];
    const float* ln2_g        = (const float*)d_in[25];
    const float* ln2_b        = (const float*)d_in[26];
    const float* mlp_w1       = (const float*)d_in[27];
    const float* mlp_b1       = (const float*)d_in[28];
    const float* mlp_w2       = (const float*)d_in[29];
    const float* mlp_b2       = (const float*)d_in[30];
    const float* imp_w        = (const float*)d_in[31];
    const float* imp_b        = (const float*)d_in[32];

    float* out0      = (float*)d_out;
    float* out_gadj  = out0 + (size_t)BATCH*NBANDS*DIM;          // +20480
    float* out_local = out_gadj + (size_t)BATCH*NBANDS*NBANDS;   // +400

    const size_t BIG = (size_t)NBANDS*BATCH*NNODE*DIM;           // 1,310,720 elems
    unsigned short* xtb = (unsigned short*)d_ws;                 // bf16 [k,b,n,d]
    unsigned short* aab = xtb + BIG;                             // bf16 a  (reused as y)
    unsigned short* bbb = aab + BIG;                             // bf16 bp
    unsigned short* yb  = aab;                                   // reuse: aa dead after k_dyn_comb
    float* fp = (float*)(bbb + BIG);
    float* combw  = fp; fp += (size_t)NBANDS*BATCH*NNODE*NNODE;  // 327,680
    float* sbase  = fp; fp += NBANDS*NNODE*NNODE;                // 20,480
    float* gbase  = fp; fp += 32;
    float* scalew = fp; fp += BATCH*SEQ*DIM;
    float* qkvw   = fp; fp += BATCH*SEQ*3*DIM;
    float* ows    = fp; fp += BATCH*SEQ*DIM;
    float* h1w    = fp; fp += BATCH*SEQ*DIM;
    float* mhw    = fp; fp += BATCH*SEQ*4*DIM;
    float* sew    = fp; fp += BATCH*SEQ*DIM;
    float* gaw    = fp; fp += BATCH*SEQ*DIM;
    float* gbw    = fp; fp += BATCH*SEQ*DIM;
    float* gcombw = fp; fp += 512;
    float* goutw  = fp; fp += BATCH*SEQ*DIM;
    // total ws: ~10.4 MB

    k_bases<<<NBANDS*NNODE + 1, 64, 0, stream>>>(l_adj_w, l_pos_enc, l_pos_factor,
                                                 g_adj_w, g_pos_enc, g_pos_factor,
                                                 sbase, gbase);
    k_transpose_feat<<<NBANDS*BATCH, 256, 0, stream>>>(feature, xtb);
    k_ab<<<NBANDS*BATCH*8, 256, 0, stream>>>(xtb, l_sim_w1, l_sim_b1, aab, bbb);
    k_dyn_comb<<<NBANDS*BATCH*16, 256, 0, stream>>>(aab, bbb, l_sim_w2, l_sim_b2, sbase, combw);
    k_y<<<NBANDS*BATCH*8, 256, 0, stream>>>(combw, xtb, yb);
    k_gcn<<<NBANDS*BATCH*8, 256, 0, stream>>>(yb, l_gcn_w, l_gcn_b, out_local);
    k_scale<<<NBANDS*BATCH, 256, 0, stream>>>(out_local, scalew);
    k_qkv<<<BATCH*SEQ, 256, 0, stream>>>(scalew, qkv_w, qkv_b, qkvw);
    k_attn<<<BATCH, 256, 0, stream>>>(qkvw, ows);
    k_proj_ln1<<<BATCH*SEQ, 256, 0, stream>>>(ows, attn_ow, attn_ob, scalew, ln1_g, ln1_b, h1w);
    k_mlp1<<<BATCH*SEQ, 256, 0, stream>>>(h1w, mlp_w1, mlp_b1, mhw);
    k_mlp2_ln2<<<BATCH*SEQ, 256, 0, stream>>>(mhw, mlp_w2, mlp_b2, h1w, ln2_g, ln2_b, sew);
    k_gab<<<BATCH*SEQ, 256, 0, stream>>>(sew, g_sim_w1, g_sim_b1, gaw, gbw);
    k_gadj<<<BATCH, 256, 0, stream>>>(gaw, gbw, g_sim_w2, g_sim_b2, gbase, gcombw, out_gadj);
    k_gout<<<BATCH*SEQ, 256, 0, stream>>>(gcombw, sew, g_gcn_w, g_gcn_b, goutw);
    k_final<<<BATCH*NBANDS, 256, 0, stream>>>(out_local, goutw, imp_w, imp_b, out0);
}

// Round 4
// 305.076 us; speedup vs baseline: 1.1615x; 1.1615x over previous
//
#include <hip/hip_runtime.h>
#include <hip/hip_bf16.h>

#define NBANDS 5
#define BATCH  16
#define DIM    256
#define NNODE  64
#define SEQ    5
#define NHEAD  4
#define DHEAD  64

typedef __hip_bfloat16 bf16;

__device__ __forceinline__ float bu2f(unsigned short u){
    bf16 h = *reinterpret_cast<bf16*>(&u);
    return __bfloat162float(h);
}
__device__ __forceinline__ unsigned short f2bu(float x){
    bf16 h = __float2bfloat16(x);
    return *reinterpret_cast<unsigned short*>(&h);
}

// ---- bases: per-band softmax(adj_w)+pf*softmax(pos_enc); global base; zeros ----
__global__ void k_bases(const float* __restrict__ l_adj_w, const float* __restrict__ l_pos_enc,
                        const float* __restrict__ l_pf,
                        const float* __restrict__ g_adj_w, const float* __restrict__ g_pos_enc,
                        const float* __restrict__ g_pf,
                        float* __restrict__ sbase, float* __restrict__ gbase,
                        float* __restrict__ zbuf)
{
    int blk = blockIdx.x;
    int t = threadIdx.x;
    if (blk < NBANDS*NNODE) {
        int k = blk / NNODE, i = blk % NNODE;
        float aw = l_adj_w[(k*NNODE + i)*NNODE + t];
        float pe = l_pos_enc[(k*NNODE + i)*NNODE + t];
        float m1 = aw, m2 = pe;
        for (int o=32;o>0;o>>=1){ m1 = fmaxf(m1, __shfl_xor(m1,o,64)); m2 = fmaxf(m2, __shfl_xor(m2,o,64)); }
        float e1 = __expf(aw-m1), e2 = __expf(pe-m2);
        float s1=e1, s2=e2;
        for (int o=32;o>0;o>>=1){ s1 += __shfl_xor(s1,o,64); s2 += __shfl_xor(s2,o,64); }
        float pf = l_pf[k];
        sbase[(k*NNODE+i)*NNODE + t] = e1/s1 + pf*(e2/s2);
    } else if (blk == NBANDS*NNODE) {
        if (t < NBANDS) {
            int i = t;
            float r1[NBANDS], r2[NBANDS];
            float m1=-1e30f, m2=-1e30f;
            for (int j=0;j<NBANDS;j++){
                r1[j]=g_adj_w[i*NBANDS+j]; r2[j]=g_pos_enc[i*NBANDS+j];
                m1=fmaxf(m1,r1[j]); m2=fmaxf(m2,r2[j]);
            }
            float s1=0.f,s2=0.f;
            for (int j=0;j<NBANDS;j++){ r1[j]=__expf(r1[j]-m1); r2[j]=__expf(r2[j]-m2); s1+=r1[j]; s2+=r2[j]; }
            float pf = g_pf[0];
            for (int j=0;j<NBANDS;j++) gbase[i*NBANDS+j] = r1[j]/s1 + pf*(r2[j]/s2);
        }
    } else {
        for (int i=t;i<DIM;i+=64) zbuf[i] = 0.f;
    }
}

// ---------------- feature f32 [B,5*D,1,N] -> xtb bf16 [k,b,n,d] -------------
__global__ void k_transpose_feat(const float* __restrict__ feat,
                                 unsigned short* __restrict__ xtb)
{
    int k = blockIdx.x / BATCH, b = blockIdx.x % BATCH;
    __shared__ unsigned short tile[64][65];
    const float* src = feat + ((size_t)b*NBANDS*DIM + (size_t)k*DIM)*NNODE; // [D][N]
    unsigned short* dst = xtb + (size_t)(k*BATCH+b)*NNODE*DIM;              // [N][D]
    int tid = threadIdx.x;
    for (int dt=0; dt<4; ++dt){
        for (int r=0;r<16;r++){
            int dp = r*4 + (tid>>6);
            int n  = tid & 63;
            tile[dp][n] = f2bu(src[(size_t)(dt*64+dp)*NNODE + n]);
        }
        __syncthreads();
        for (int r=0;r<16;r++){
            int n  = r*4 + (tid>>6);
            int dp = tid & 63;
            dst[(size_t)n*DIM + dt*64 + dp] = tile[dp][n];
        }
        __syncthreads();
    }
}

// ---- a/bp: 16 rows/block, thread owns 1 A-col + 1 B-col; b128 x broadcasts ----
__global__ void __launch_bounds__(256) k_ab(const unsigned short* __restrict__ xtb,
                     const float* __restrict__ w1, const float* __restrict__ b1,
                     unsigned short* __restrict__ aab, unsigned short* __restrict__ bbb)
{
    int blk = blockIdx.x;                 // 5*16*4
    int k = blk / (BATCH*4);
    int b = (blk/4) % BATCH;
    int i0 = (blk & 3) * 16;
    int kb = k*BATCH + b;
    __shared__ float xr[DIM][20];         // [dp][row], pad 20 keeps 16B align
    int tid = threadIdx.x;
    for (int u=0; u<16; ++u){
        int idx = u*256 + tid;            // 0..4095
        int r = idx >> 8, d = idx & 255;
        xr[d][r] = bu2f(xtb[((size_t)kb*NNODE + i0 + r)*DIM + d]);
    }
    __syncthreads();
    const float* WA = w1 + (size_t)k*2*DIM*DIM + tid;
    const float* WB = WA + (size_t)DIM*DIM;
    float accA[16], accB[16];
    #pragma unroll
    for (int r=0;r<16;r++){ accA[r]=0.f; accB[r]=0.f; }
    #pragma unroll 4
    for (int dp=0; dp<DIM; ++dp){
        float wa = WA[(size_t)dp*DIM];
        float wb = WB[(size_t)dp*DIM];
        float4 xq[4];
        xq[0] = *reinterpret_cast<const float4*>(&xr[dp][0]);
        xq[1] = *reinterpret_cast<const float4*>(&xr[dp][4]);
        xq[2] = *reinterpret_cast<const float4*>(&xr[dp][8]);
        xq[3] = *reinterpret_cast<const float4*>(&xr[dp][12]);
        const float* xv = reinterpret_cast<const float*>(xq);
        #pragma unroll
        for (int r=0;r<16;r++){
            accA[r] += xv[r]*wa;
            accB[r] += xv[r]*wb;
        }
    }
    float bias = b1[k*DIM + tid];
    for (int r=0;r<16;r++){
        size_t idx = ((size_t)kb*NNODE + i0 + r)*DIM + tid;
        aab[idx] = f2bu(accA[r] + bias);
        bbb[idx] = f2bu(accB[r]);
    }
}

// ------- dyn = sigmoid(sum_d elu(a_i+bp_j)*w2 + b2); comb = softmax row -----
__global__ void k_dyn_comb(const unsigned short* __restrict__ aab,
                           const unsigned short* __restrict__ bbb,
                           const float* __restrict__ w2, const float* __restrict__ b2arr,
                           const float* __restrict__ sbase,
                           float* __restrict__ comb)
{
    int blk = blockIdx.x;                     // NBANDS*BATCH*16 blocks, 4 i-rows each
    int k = blk / (BATCH*16);
    int b = (blk / 16) % BATCH;
    int i0 = (blk % 16) * 4;
    int kb = k*BATCH + b;
    __shared__ float arows[4][DIM];
    __shared__ float w2s[DIM];
    __shared__ float dyn_s[4][NNODE];
    int tid = threadIdx.x;
    int wave = tid >> 6, lane = tid & 63;
    for (int r=0;r<4;r++) arows[r][tid] = bu2f(aab[((size_t)kb*NNODE + i0 + r)*DIM + tid]);
    w2s[tid] = w2[k*DIM + tid];
    __syncthreads();
    const unsigned short* bpbase = bbb + (size_t)kb*NNODE*DIM;
    for (int jt=0; jt<16; ++jt){
        int j = jt*4 + wave;
        const unsigned short* bj = bpbase + (size_t)j*DIM;
        float acc[4] = {0.f,0.f,0.f,0.f};
        #pragma unroll
        for (int m=0;m<4;m++){
            int dd = lane + m*64;
            float bpv = bu2f(bj[dd]);
            float wv  = w2s[dd];
            #pragma unroll
            for (int r=0;r<4;r++){
                float v = arows[r][dd] + bpv;
                float e = (v > 0.f) ? v : (__expf(v) - 1.f);   // elu
                acc[r] += e*wv;
            }
        }
        #pragma unroll
        for (int r=0;r<4;r++){
            float s = acc[r];
            for (int o=32;o>0;o>>=1) s += __shfl_xor(s,o,64);
            if (lane==0) dyn_s[r][j] = s;
        }
    }
    __syncthreads();
    {
        float sb2 = b2arr[k];
        float t = dyn_s[wave][lane] + sb2;
        float sg = 1.f/(1.f + __expf(-t));
        float val = sbase[(k*NNODE + i0 + wave)*NNODE + lane] + sg;
        float m = val;
        for (int o=32;o>0;o>>=1) m = fmaxf(m, __shfl_xor(m,o,64));
        float e = __expf(val - m);
        float s = e;
        for (int o=32;o>0;o>>=1) s += __shfl_xor(s,o,64);
        comb[((size_t)kb*NNODE + i0 + wave)*NNODE + lane] = e/s;
    }
}

// ---------------- y = comb @ xt, 16 rows/block, b128 comb broadcasts --------
__global__ void __launch_bounds__(256) k_y(const float* __restrict__ comb,
                   const unsigned short* __restrict__ xtb,
                   unsigned short* __restrict__ yb)
{
    int blk = blockIdx.x;                 // 5*16*4
    int k = blk / (BATCH*4);
    int b = (blk/4) % BATCH;
    int i0 = (blk & 3) * 16;
    int kb = k*BATCH + b;
    __shared__ float ct[NNODE][20];       // [j][row]
    int tid = threadIdx.x;
    for (int u=0; u<4; ++u){
        int idx = u*256 + tid;            // 0..1023
        int i = idx >> 6, j = idx & 63;
        ct[j][i] = comb[((size_t)kb*NNODE + i0 + i)*NNODE + j];
    }
    __syncthreads();
    const unsigned short* xb = xtb + (size_t)kb*NNODE*DIM + tid;
    float acc[16];
    #pragma unroll
    for (int r=0;r<16;r++) acc[r]=0.f;
    #pragma unroll 4
    for (int j=0;j<NNODE;++j){
        float xv = bu2f(xb[(size_t)j*DIM]);
        float4 cq[4];
        cq[0] = *reinterpret_cast<const float4*>(&ct[j][0]);
        cq[1] = *reinterpret_cast<const float4*>(&ct[j][4]);
        cq[2] = *reinterpret_cast<const float4*>(&ct[j][8]);
        cq[3] = *reinterpret_cast<const float4*>(&ct[j][12]);
        const float* cv = reinterpret_cast<const float*>(cq);
        #pragma unroll
        for (int r=0;r<16;r++) acc[r] += cv[r]*xv;
    }
    for (int r=0;r<16;r++) yb[((size_t)kb*NNODE + i0 + r)*DIM + tid] = f2bu(acc[r]);
}

// ---- z = y @ gcn_w + b -> out_local [b,k,d,n] f32; 16 rows, 2 cols/thread ----
__global__ void __launch_bounds__(128) k_gcn(const unsigned short* __restrict__ yb,
                     const float* __restrict__ gw, const float* __restrict__ gb,
                     float* __restrict__ out_local)
{
    int blk = blockIdx.x;                 // 5*16*4
    int k = blk / (BATCH*4);
    int b = (blk/4) % BATCH;
    int i0 = (blk & 3) * 16;
    int kb = k*BATCH + b;
    __shared__ float yr[DIM][20];         // [dp][row]
    int tid = threadIdx.x;                // 0..127
    for (int u=0; u<32; ++u){
        int idx = u*128 + tid;            // 0..4095
        int r = idx >> 8, d = idx & 255;
        yr[d][r] = bu2f(yb[((size_t)kb*NNODE + i0 + r)*DIM + d]);
    }
    __syncthreads();
    const float* W = gw + (size_t)k*DIM*DIM;
    float acc0[16], acc1[16];
    #pragma unroll
    for (int r=0;r<16;r++){ acc0[r]=0.f; acc1[r]=0.f; }
    #pragma unroll 4
    for (int dp=0;dp<DIM;++dp){
        float w0 = W[(size_t)dp*DIM + tid];
        float w1v = W[(size_t)dp*DIM + tid + 128];
        float4 xq[4];
        xq[0] = *reinterpret_cast<const float4*>(&yr[dp][0]);
        xq[1] = *reinterpret_cast<const float4*>(&yr[dp][4]);
        xq[2] = *reinterpret_cast<const float4*>(&yr[dp][8]);
        xq[3] = *reinterpret_cast<const float4*>(&yr[dp][12]);
        const float* xv = reinterpret_cast<const float*>(xq);
        #pragma unroll
        for (int r=0;r<16;r++){
            acc0[r] += xv[r]*w0;
            acc1[r] += xv[r]*w1v;
        }
    }
    float b0 = gb[k*DIM + tid], b1v = gb[k*DIM + tid + 128];
    float* d0 = out_local + ((size_t)(b*NBANDS + k)*DIM + tid)*NNODE + i0;
    float* d1 = out_local + ((size_t)(b*NBANDS + k)*DIM + tid + 128)*NNODE + i0;
    #pragma unroll
    for (int q=0;q<4;q++){
        reinterpret_cast<float4*>(d0)[q] = make_float4(acc0[q*4]+b0, acc0[q*4+1]+b0, acc0[q*4+2]+b0, acc0[q*4+3]+b0);
        reinterpret_cast<float4*>(d1)[q] = make_float4(acc1[q*4]+b1v, acc1[q*4+1]+b1v, acc1[q*4+2]+b1v, acc1[q*4+3]+b1v);
    }
}

// ---------------- scale_nodes[b,k,d] = mean_n local_out[b,k,d,n] ------------
__global__ void k_scale(const float* __restrict__ out_local, float* __restrict__ scalew)
{
    int k = blockIdx.x / BATCH, b = blockIdx.x % BATCH;
    int d = threadIdx.x;
    const float4* zl = reinterpret_cast<const float4*>(out_local + ((size_t)(b*NBANDS + k)*DIM + d)*NNODE);
    float acc = 0.f;
    #pragma unroll
    for (int q=0;q<16;++q){
        float4 v = zl[q];
        acc += v.x + v.y + v.z + v.w;
    }
    scalew[((size_t)b*SEQ + k)*DIM + d] = acc * (1.f/64.f);
}

// ---- generic sliced GEMV: out[row][n] = act(bias[n] + sum_k x[row][k] w[k][n]) ----
template<int COLS, int SLICES>
__global__ void __launch_bounds__(256) k_gemv(const float* __restrict__ x, const float* __restrict__ w,
                       const float* __restrict__ bias, float* __restrict__ out,
                       int K, int N, int act)
{
    int chunks = N / COLS;
    int row = blockIdx.x / chunks;
    int n0 = (blockIdx.x % chunks) * COLS;
    int c = threadIdx.x % COLS, s = threadIdx.x / COLS;
    __shared__ float xs[1024];
    __shared__ float part[SLICES][COLS];
    for (int i = threadIdx.x; i < K; i += 256) xs[i] = x[(size_t)row*K + i];
    __syncthreads();
    int klen = K / SLICES;
    const float* wp = w + (size_t)(s*klen)*N + n0 + c;
    const float* xp = xs + s*klen;
    float acc = 0.f;
    #pragma unroll 8
    for (int i = 0; i < klen; ++i) acc += xp[i] * wp[(size_t)i*N];
    part[s][c] = acc;
    __syncthreads();
    if (s == 0){
        float v = bias[n0+c];
        #pragma unroll
        for (int q=0;q<SLICES;q++) v += part[q][c];
        if (act) v = 0.5f*v*(1.f + erff(v*0.70710678118654752f));
        out[(size_t)row*N + n0 + c] = v;
    }
}

// ---------------- MHA core: scores, softmax, att@v -> o_ws ------------------
__global__ void k_attn(const float* __restrict__ qkvw, float* __restrict__ ows)
{
    int b = blockIdx.x;
    int tid = threadIdx.x;
    int h = tid >> 6, l = tid & 63;
    __shared__ float att[NHEAD][SEQ][SEQ];
    const float* base = qkvw + (size_t)b*SEQ*3*DIM;
    for (int i=0;i<SEQ;i++){
        float qv = base[(size_t)i*3*DIM + h*DHEAD + l];
        for (int j=0;j<SEQ;j++){
            float kv = base[(size_t)j*3*DIM + DIM + h*DHEAD + l];
            float p = qv * kv;
            for (int o=32;o>0;o>>=1) p += __shfl_xor(p,o,64);
            if (l==0) att[h][i][j] = p * 0.125f;
        }
    }
    __syncthreads();
    if (l == 0){
        for (int i=0;i<SEQ;i++){
            float m=-1e30f;
            for (int j=0;j<SEQ;j++) m = fmaxf(m, att[h][i][j]);
            float e[SEQ]; float s=0.f;
            for (int j=0;j<SEQ;j++){ e[j] = __expf(att[h][i][j]-m); s+=e[j]; }
            for (int j=0;j<SEQ;j++) att[h][i][j] = e[j]/s;
        }
    }
    __syncthreads();
    for (int i=0;i<SEQ;i++){
        float acc=0.f;
        for (int j=0;j<SEQ;j++) acc += att[h][i][j] * base[(size_t)j*3*DIM + 2*DIM + h*DHEAD + l];
        ows[((size_t)b*SEQ + i)*DIM + h*DHEAD + l] = acc;
    }
}

// ---------------- block LayerNorm over 256 elems ----------------------------
__device__ __forceinline__ float block_ln(float v, int tid, float* red, float g, float bln)
{
    float s = v;
    for (int o=32;o>0;o>>=1) s += __shfl_xor(s,o,64);
    int wave = tid>>6, lane = tid&63;
    if (lane==0) red[wave] = s;
    __syncthreads();
    float mean = (red[0]+red[1]+red[2]+red[3]) * (1.f/DIM);
    float c = v - mean;
    float q = c*c;
    for (int o=32;o>0;o>>=1) q += __shfl_xor(q,o,64);
    __syncthreads();
    if (lane==0) red[wave] = q;
    __syncthreads();
    float var = (red[0]+red[1]+red[2]+red[3]) * (1.f/DIM);
    return c * rsqrtf(var + 1e-5f) * g + bln;
}

// ---------------- residual + LN: out = LN(a+r)*g + be -----------------------
__global__ void k_ln(const float* __restrict__ a, const float* __restrict__ r,
                     const float* __restrict__ g, const float* __restrict__ be,
                     float* __restrict__ out)
{
    int row = blockIdx.x;
    int d = threadIdx.x;
    __shared__ float red[4];
    float v = a[(size_t)row*DIM + d] + r[(size_t)row*DIM + d];
    out[(size_t)row*DIM + d] = block_ln(v, d, red, g[d], be[d]);
}

// ---------------- global adj: dyn, comb softmax -> gcomb ws + f32 out -------
__global__ void k_gadj(const float* __restrict__ gaw, const float* __restrict__ gbw,
                       const float* __restrict__ gw2, const float* __restrict__ gb2,
                       const float* __restrict__ gbase,
                       float* __restrict__ gcombw, float* __restrict__ out_gadj)
{
    int b = blockIdx.x;
    int tid = threadIdx.x;
    int wave = tid>>6, lane = tid&63;
    __shared__ float dyn[SEQ][SEQ];
    __shared__ float w2s[DIM];
    w2s[tid] = gw2[tid];
    __syncthreads();
    for (int p = wave; p < SEQ*SEQ; p += 4){
        int i = p / SEQ, j = p % SEQ;
        const float* gar = gaw + ((size_t)b*SEQ+i)*DIM;
        const float* gbr = gbw + ((size_t)b*SEQ+j)*DIM;
        float acc = 0.f;
        #pragma unroll
        for (int m=0;m<4;m++){
            int dd = lane + m*64;
            float v = gar[dd] + gbr[dd];
            float e = (v>0.f) ? v : (__expf(v)-1.f);
            acc += e * w2s[dd];
        }
        for (int o=32;o>0;o>>=1) acc += __shfl_xor(acc,o,64);
        if (lane==0) dyn[i][j] = acc;
    }
    __syncthreads();
    if (tid < SEQ){
        int i = tid;
        float sb2 = gb2[0];
        float row[SEQ]; float m=-1e30f;
        for (int j=0;j<SEQ;j++){
            float sg = 1.f/(1.f+__expf(-(dyn[i][j]+sb2)));
            row[j] = gbase[i*SEQ+j] + sg;
            m = fmaxf(m,row[j]);
        }
        float ssum=0.f;
        for (int j=0;j<SEQ;j++){ row[j]=__expf(row[j]-m); ssum+=row[j]; }
        for (int j=0;j<SEQ;j++){
            float c = row[j]/ssum;
            gcombw[((size_t)b*SEQ+i)*SEQ + j] = c;
            out_gadj[((size_t)b*SEQ+i)*SEQ + j] = c;
        }
    }
}

// ---------------- trow[row][d] = sum_j gcomb[row][j]*se[b,j,d] --------------
__global__ void k_gmix(const float* __restrict__ gcombw, const float* __restrict__ sew,
                       float* __restrict__ trow)
{
    int row = blockIdx.x;          // b*SEQ+k
    int b = row / SEQ;
    int d = threadIdx.x;
    float t = 0.f;
    #pragma unroll
    for (int j=0;j<SEQ;j++) t += gcombw[row*SEQ + j] * sew[((size_t)b*SEQ + j)*DIM + d];
    trow[(size_t)row*DIM + d] = t;
}

// ------- final: out0[b,k,d] = gout[b,k,d] * (sum_n local_out*imp_w) + imp_b --
__global__ void k_final(const float* __restrict__ out_local,
                        const float* __restrict__ goutw,
                        const float* __restrict__ imp_w, const float* __restrict__ imp_b,
                        float* __restrict__ out0)
{
    int b = blockIdx.x / NBANDS, k = blockIdx.x % NBANDS;
    __shared__ float iw[NNODE];
    int d = threadIdx.x;
    if (d < NNODE) iw[d] = imp_w[k*NNODE + d];
    __syncthreads();
    const float4* zl = reinterpret_cast<const float4*>(out_local + ((size_t)(b*NBANDS + k)*DIM + d)*NNODE);
    float acc = 0.f;
    #pragma unroll
    for (int q=0;q<16;++q){
        float4 v = zl[q];
        acc += v.x*iw[q*4] + v.y*iw[q*4+1] + v.z*iw[q*4+2] + v.w*iw[q*4+3];
    }
    float val = goutw[((size_t)b*NBANDS+k)*DIM + d] * acc + imp_b[k];
    out0[((size_t)b*NBANDS+k)*DIM + d] = val;
}

extern "C" void kernel_launch(void* const* d_in, const int* in_sizes, int n_in,
                              void* d_out, int out_size, void* d_ws, size_t ws_size,
                              hipStream_t stream)
{
    const float* feature      = (const float*)d_in[0];
    const float* l_adj_w      = (const float*)d_in[1];
    const float* l_sim_w1     = (const float*)d_in[2];
    const float* l_sim_b1     = (const float*)d_in[3];
    const float* l_sim_w2     = (const float*)d_in[4];
    const float* l_sim_b2     = (const float*)d_in[5];
    const float* l_pos_factor = (const float*)d_in[6];
    const float* l_pos_enc    = (const float*)d_in[7];
    const float* l_gcn_w      = (const float*)d_in[8];
    const float* l_gcn_b      = (const float*)d_in[9];
    const float* g_adj_w      = (const float*)d_in[10];
    const float* g_sim_w1     = (const float*)d_in[11];
    const float* g_sim_b1     = (const float*)d_in[12];
    const float* g_sim_w2     = (const float*)d_in[13];
    const float* g_sim_b2     = (const float*)d_in[14];
    const float* g_pos_factor = (const float*)d_in[15];
    const float* g_pos_enc    = (const float*)d_in[16];
    const float* g_gcn_w      = (const float*)d_in[17];
    const float* g_gcn_b      = (const float*)d_in[18];
    const float* qkv_w        = (const float*)d_in[19];
    const float* qkv_b        = (const float*)d_in[20];
    const float* attn_ow      = (const float*)d_in[21];
    const float* attn_ob      = (const float*)d_in[22];
    const float* ln1_g        = (const float*)d_in[23];
    const float* ln1_b        = (const float*)d_in[24];
    const float* ln2_g        = (const float*)d_in[25];
    const float* ln2_b        = (const float*)d_in[26];
    const float* mlp_w1       = (const float*)d_in[27];
    const float* mlp_b1       = (const float*)d_in[28];
    const float* mlp_w2       = (const float*)d_in[29];
    const float* mlp_b2       = (const float*)d_in[30];
    const float* imp_w        = (const float*)d_in[31];
    const float* imp_b        = (const float*)d_in[32];

    float* out0      = (float*)d_out;
    float* out_gadj  = out0 + (size_t)BATCH*NBANDS*DIM;
    float* out_local = out_gadj + (size_t)BATCH*NBANDS*NBANDS;

    const size_t BIG = (size_t)NBANDS*BATCH*NNODE*DIM;           // 1,310,720 elems
    unsigned short* xtb = (unsigned short*)d_ws;                 // bf16 [k,b,n,d]
    unsigned short* aab = xtb + BIG;                             // bf16 a (reused as y)
    unsigned short* bbb = aab + BIG;                             // bf16 bp
    unsigned short* yb  = aab;
    float* fp = (float*)(bbb + BIG);
    float* combw  = fp; fp += (size_t)NBANDS*BATCH*NNODE*NNODE;
    float* sbase  = fp; fp += NBANDS*NNODE*NNODE;
    float* gbase  = fp; fp += 32;
    float* zbuf   = fp; fp += DIM;
    float* scalew = fp; fp += BATCH*SEQ*DIM;
    float* qkvw   = fp; fp += BATCH*SEQ*3*DIM;
    float* ows    = fp; fp += BATCH*SEQ*DIM;
    float* projw  = fp; fp += BATCH*SEQ*DIM;
    float* h1w    = fp; fp += BATCH*SEQ*DIM;
    float* mhw    = fp; fp += BATCH*SEQ*4*DIM;
    float* m2w    = fp; fp += BATCH*SEQ*DIM;
    float* sew    = fp; fp += BATCH*SEQ*DIM;
    float* gaw    = fp; fp += BATCH*SEQ*DIM;
    float* gbw    = fp; fp += BATCH*SEQ*DIM;
    float* gcombw = fp; fp += 512;
    float* trow   = fp; fp += BATCH*SEQ*DIM;
    float* goutw  = fp; fp += BATCH*SEQ*DIM;

    const int ROWS = BATCH*SEQ;   // 80

    k_bases<<<NBANDS*NNODE + 2, 64, 0, stream>>>(l_adj_w, l_pos_enc, l_pos_factor,
                                                 g_adj_w, g_pos_enc, g_pos_factor,
                                                 sbase, gbase, zbuf);
    k_transpose_feat<<<NBANDS*BATCH, 256, 0, stream>>>(feature, xtb);
    k_ab<<<NBANDS*BATCH*4, 256, 0, stream>>>(xtb, l_sim_w1, l_sim_b1, aab, bbb);
    k_dyn_comb<<<NBANDS*BATCH*16, 256, 0, stream>>>(aab, bbb, l_sim_w2, l_sim_b2, sbase, combw);
    k_y<<<NBANDS*BATCH*4, 256, 0, stream>>>(combw, xtb, yb);
    k_gcn<<<NBANDS*BATCH*4, 128, 0, stream>>>(yb, l_gcn_w, l_gcn_b, out_local);
    k_scale<<<NBANDS*BATCH, 256, 0, stream>>>(out_local, scalew);
    k_gemv<64,4><<<ROWS*12, 256, 0, stream>>>(scalew, qkv_w, qkv_b, qkvw, 256, 768, 0);
    k_attn<<<BATCH, 256, 0, stream>>>(qkvw, ows);
    k_gemv<64,4><<<ROWS*4, 256, 0, stream>>>(ows, attn_ow, attn_ob, projw, 256, 256, 0);
    k_ln<<<ROWS, 256, 0, stream>>>(projw, scalew, ln1_g, ln1_b, h1w);
    k_gemv<64,4><<<ROWS*16, 256, 0, stream>>>(h1w, mlp_w1, mlp_b1, mhw, 256, 1024, 1);
    k_gemv<32,8><<<ROWS*8, 256, 0, stream>>>(mhw, mlp_w2, mlp_b2, m2w, 1024, 256, 0);
    k_ln<<<ROWS, 256, 0, stream>>>(m2w, h1w, ln2_g, ln2_b, sew);
    k_gemv<64,4><<<ROWS*4, 256, 0, stream>>>(sew, g_sim_w1, g_sim_b1, gaw, 256, 256, 0);
    k_gemv<64,4><<<ROWS*4, 256, 0, stream>>>(sew, g_sim_w1 + (size_t)DIM*DIM, zbuf, gbw, 256, 256, 0);
    k_gadj<<<BATCH, 256, 0, stream>>>(gaw, gbw, g_sim_w2, g_sim_b2, gbase, gcombw, out_gadj);
    k_gmix<<<ROWS, 256, 0, stream>>>(gcombw, sew, trow);
    k_gemv<64,4><<<ROWS*4, 256, 0, stream>>>(trow, g_gcn_w, g_gcn_b, goutw, 256, 256, 0);
    k_final<<<BATCH*NBANDS, 256, 0, stream>>>(out_local, goutw, imp_w, imp_b, out0);
}

// Round 5
// 264.716 us; speedup vs baseline: 1.3386x; 1.1525x over previous
//
#include <hip/hip_runtime.h>
#include <hip/hip_bf16.h>

#define NBANDS 5
#define BATCH  16
#define DIM    256
#define NNODE  64
#define SEQ    5
#define NHEAD  4
#define DHEAD  64

typedef __hip_bfloat16 bf16;
typedef unsigned short ushort_t;
typedef __attribute__((ext_vector_type(8))) short short8;   // 8 bf16 (4 VGPRs)
typedef __attribute__((ext_vector_type(4))) float float4v;  // 4 fp32 acc

__device__ __forceinline__ float bu2f(ushort_t u){
    bf16 h = *reinterpret_cast<bf16*>(&u);
    return __bfloat162float(h);
}
__device__ __forceinline__ ushort_t f2bu(float x){
    bf16 h = __float2bfloat16(x);
    return *reinterpret_cast<ushort_t*>(&h);
}

// ---- bases: per-band softmax(adj_w)+pf*softmax(pos_enc); global base; zeros ----
__global__ void k_bases(const float* __restrict__ l_adj_w, const float* __restrict__ l_pos_enc,
                        const float* __restrict__ l_pf,
                        const float* __restrict__ g_adj_w, const float* __restrict__ g_pos_enc,
                        const float* __restrict__ g_pf,
                        float* __restrict__ sbase, float* __restrict__ gbase,
                        float* __restrict__ zbuf)
{
    int blk = blockIdx.x;
    int t = threadIdx.x;
    if (blk < NBANDS*NNODE) {
        int k = blk / NNODE, i = blk % NNODE;
        float aw = l_adj_w[(k*NNODE + i)*NNODE + t];
        float pe = l_pos_enc[(k*NNODE + i)*NNODE + t];
        float m1 = aw, m2 = pe;
        for (int o=32;o>0;o>>=1){ m1 = fmaxf(m1, __shfl_xor(m1,o,64)); m2 = fmaxf(m2, __shfl_xor(m2,o,64)); }
        float e1 = __expf(aw-m1), e2 = __expf(pe-m2);
        float s1=e1, s2=e2;
        for (int o=32;o>0;o>>=1){ s1 += __shfl_xor(s1,o,64); s2 += __shfl_xor(s2,o,64); }
        float pf = l_pf[k];
        sbase[(k*NNODE+i)*NNODE + t] = e1/s1 + pf*(e2/s2);
    } else if (blk == NBANDS*NNODE) {
        if (t < NBANDS) {
            int i = t;
            float r1[NBANDS], r2[NBANDS];
            float m1=-1e30f, m2=-1e30f;
            for (int j=0;j<NBANDS;j++){
                r1[j]=g_adj_w[i*NBANDS+j]; r2[j]=g_pos_enc[i*NBANDS+j];
                m1=fmaxf(m1,r1[j]); m2=fmaxf(m2,r2[j]);
            }
            float s1=0.f,s2=0.f;
            for (int j=0;j<NBANDS;j++){ r1[j]=__expf(r1[j]-m1); r2[j]=__expf(r2[j]-m2); s1+=r1[j]; s2+=r2[j]; }
            float pf = g_pf[0];
            for (int j=0;j<NBANDS;j++) gbase[i*NBANDS+j] = r1[j]/s1 + pf*(r2[j]/s2);
        }
    } else {
        for (int i=t;i<DIM;i+=64) zbuf[i] = 0.f;
    }
}

// ---- weight prep: 15 instances of 256x256 transpose+bf16-convert ----------
// w1bt[k][ncol][kk] = w1[k][(ncol>>8)*256+kk][ncol&255];  gwbt[k][c][kk] = gw[k][kk][c]
__global__ void k_prep(const float* __restrict__ w1, const float* __restrict__ gw,
                       ushort_t* __restrict__ w1bt, ushort_t* __restrict__ gwbt)
{
    int blk = blockIdx.x;          // inst*16 + tile
    int inst = blk >> 4;
    int t = blk & 15;
    int r0 = (t>>2)*64, c0 = (t&3)*64;
    const float* src; ushort_t* dst;
    if (inst < 10){
        int k = inst>>1, half = inst&1;
        src = w1  + ((size_t)k*512 + half*256)*256;
        dst = w1bt+ ((size_t)k*512 + half*256)*256;
    } else {
        int k = inst-10;
        src = gw  + (size_t)k*65536;
        dst = gwbt+ (size_t)k*65536;
    }
    __shared__ ushort_t tile[64][65];
    int tid = threadIdx.x;
    int jj = tid & 63, i4 = tid >> 6;
    for (int p=0;p<16;p++){
        int i = p*4 + i4;
        tile[i][jj] = f2bu(src[(size_t)(r0+i)*256 + c0 + jj]);
    }
    __syncthreads();
    for (int p=0;p<16;p++){
        int i = p*4 + i4;
        dst[(size_t)(c0+i)*256 + r0 + jj] = tile[jj][i];
    }
}

// ---- feature f32 [B,5*D,1,N] -> xtb bf16 [k,b,n,d] AND xtT bf16 [k,b,d,n] ----
__global__ void k_transpose_feat(const float* __restrict__ feat,
                                 ushort_t* __restrict__ xtb,
                                 ushort_t* __restrict__ xtT)
{
    int k = blockIdx.x / BATCH, b = blockIdx.x % BATCH;
    __shared__ ushort_t tile[64][65];
    const float* src = feat + ((size_t)b*NBANDS*DIM + (size_t)k*DIM)*NNODE; // [D][N]
    ushort_t* dst = xtb + (size_t)(k*BATCH+b)*NNODE*DIM;                    // [N][D]
    int tid = threadIdx.x;
    // straight convert: xtT[d][n] = feature[d][n]
    ushort_t* dstT = xtT + (size_t)(k*BATCH+b)*DIM*NNODE;
    for (int u=0; u<64; ++u){
        int idx = u*256 + tid;
        dstT[idx] = f2bu(src[idx]);
    }
    // LDS transpose: xtb[n][d]
    for (int dt=0; dt<4; ++dt){
        for (int r=0;r<16;r++){
            int dp = r*4 + (tid>>6);
            int n  = tid & 63;
            tile[dp][n] = f2bu(src[(size_t)(dt*64+dp)*NNODE + n]);
        }
        __syncthreads();
        for (int r=0;r<16;r++){
            int n  = r*4 + (tid>>6);
            int dp = tid & 63;
            dst[(size_t)n*DIM + dt*64 + dp] = tile[dp][n];
        }
        __syncthreads();
    }
}

// ---- MFMA a/bp: per band GEMM [1024 x 256] @ [256 x 512] -> aab|bbb bf16 ----
__global__ void __launch_bounds__(256) k_ab_mfma(const ushort_t* __restrict__ xtb,
                        const ushort_t* __restrict__ w1bt, const float* __restrict__ b1,
                        ushort_t* __restrict__ aab, ushort_t* __restrict__ bbb)
{
    int blk = blockIdx.x;                 // 5*16*8
    int kband = blk / (BATCH*8);
    int b = (blk/8) % BATCH;
    int nblk = blk & 7;
    int tid = threadIdx.x;
    int wave = tid>>6, lane = tid&63;
    int c16 = lane & 15, quad = lane >> 4;
    int m0 = wave*16;
    size_t rowbase = (size_t)(kband*BATCH+b)*NNODE;
    const ushort_t* Aptr = xtb + (rowbase + m0 + c16)*DIM + quad*8;
    const ushort_t* Bbase = w1bt + (size_t)kband*512*DIM;
    int ncol0 = nblk*64;
    const ushort_t* Bptr0 = Bbase + (size_t)(ncol0 +  0 + c16)*DIM + quad*8;
    const ushort_t* Bptr1 = Bbase + (size_t)(ncol0 + 16 + c16)*DIM + quad*8;
    const ushort_t* Bptr2 = Bbase + (size_t)(ncol0 + 32 + c16)*DIM + quad*8;
    const ushort_t* Bptr3 = Bbase + (size_t)(ncol0 + 48 + c16)*DIM + quad*8;
    float4v acc0 = {0.f,0.f,0.f,0.f}, acc1 = acc0, acc2 = acc0, acc3 = acc0;
    #pragma unroll
    for (int ks=0; ks<8; ++ks){
        short8 a  = *reinterpret_cast<const short8*>(Aptr  + ks*32);
        short8 b0 = *reinterpret_cast<const short8*>(Bptr0 + ks*32);
        short8 b1v= *reinterpret_cast<const short8*>(Bptr1 + ks*32);
        short8 b2 = *reinterpret_cast<const short8*>(Bptr2 + ks*32);
        short8 b3 = *reinterpret_cast<const short8*>(Bptr3 + ks*32);
        acc0 = __builtin_amdgcn_mfma_f32_16x16x32_bf16(a, b0, acc0, 0,0,0);
        acc1 = __builtin_amdgcn_mfma_f32_16x16x32_bf16(a, b1v, acc1, 0,0,0);
        acc2 = __builtin_amdgcn_mfma_f32_16x16x32_bf16(a, b2, acc2, 0,0,0);
        acc3 = __builtin_amdgcn_mfma_f32_16x16x32_bf16(a, b3, acc3, 0,0,0);
    }
    int half = nblk >> 2;
    int cbase = (nblk & 3)*64;
    ushort_t* dst = half ? bbb : aab;
    float4v accs[4] = {acc0, acc1, acc2, acc3};
    #pragma unroll
    for (int nt=0; nt<4; ++nt){
        int cg = cbase + nt*16 + c16;
        float bias = half ? 0.f : b1[kband*DIM + cg];
        #pragma unroll
        for (int r=0;r<4;r++){
            int m = m0 + quad*4 + r;
            dst[(rowbase + m)*DIM + cg] = f2bu(accs[nt][r] + bias);
        }
    }
}

// ------- dyn = sigmoid(sum_d elu(a_i+bp_j)*w2 + b2); comb = softmax (bf16) ---
__global__ void k_dyn_comb(const ushort_t* __restrict__ aab,
                           const ushort_t* __restrict__ bbb,
                           const float* __restrict__ w2, const float* __restrict__ b2arr,
                           const float* __restrict__ sbase,
                           ushort_t* __restrict__ combb)
{
    int blk = blockIdx.x;                     // NBANDS*BATCH*16 blocks, 4 i-rows each
    int k = blk / (BATCH*16);
    int b = (blk / 16) % BATCH;
    int i0 = (blk % 16) * 4;
    int kb = k*BATCH + b;
    __shared__ float arows[4][DIM];
    __shared__ float w2s[DIM];
    __shared__ float dyn_s[4][NNODE];
    int tid = threadIdx.x;
    int wave = tid >> 6, lane = tid & 63;
    for (int r=0;r<4;r++) arows[r][tid] = bu2f(aab[((size_t)kb*NNODE + i0 + r)*DIM + tid]);
    w2s[tid] = w2[k*DIM + tid];
    __syncthreads();
    const ushort_t* bpbase = bbb + (size_t)kb*NNODE*DIM;
    for (int jt=0; jt<16; ++jt){
        int j = jt*4 + wave;
        const ushort_t* bj = bpbase + (size_t)j*DIM;
        float acc[4] = {0.f,0.f,0.f,0.f};
        #pragma unroll
        for (int m=0;m<4;m++){
            int dd = lane + m*64;
            float bpv = bu2f(bj[dd]);
            float wv  = w2s[dd];
            #pragma unroll
            for (int r=0;r<4;r++){
                float v = arows[r][dd] + bpv;
                float e = (v > 0.f) ? v : (__expf(v) - 1.f);   // elu
                acc[r] += e*wv;
            }
        }
        #pragma unroll
        for (int r=0;r<4;r++){
            float s = acc[r];
            for (int o=32;o>0;o>>=1) s += __shfl_xor(s,o,64);
            if (lane==0) dyn_s[r][j] = s;
        }
    }
    __syncthreads();
    {
        float sb2 = b2arr[k];
        float t = dyn_s[wave][lane] + sb2;
        float sg = 1.f/(1.f + __expf(-t));
        float val = sbase[(k*NNODE + i0 + wave)*NNODE + lane] + sg;
        float m = val;
        for (int o=32;o>0;o>>=1) m = fmaxf(m, __shfl_xor(m,o,64));
        float e = __expf(val - m);
        float s = e;
        for (int o=32;o>0;o>>=1) s += __shfl_xor(s,o,64);
        combb[((size_t)kb*NNODE + i0 + wave)*NNODE + lane] = f2bu(e/s);
    }
}

// ---- MFMA y: per (k,b) GEMM [64 x 64] @ [64 x 256] -> yb bf16 [kb][n][d] ----
__global__ void __launch_bounds__(256) k_y_mfma(const ushort_t* __restrict__ combb,
                       const ushort_t* __restrict__ xtT,
                       ushort_t* __restrict__ yb)
{
    int blk = blockIdx.x;                 // 5*16*4
    int kband = blk / (BATCH*4);
    int b = (blk/4) % BATCH;
    int nblk = blk & 3;
    int tid = threadIdx.x;
    int wave = tid>>6, lane = tid&63;
    int c16 = lane & 15, quad = lane >> 4;
    int m0 = wave*16;
    int kb = kband*BATCH + b;
    const ushort_t* Aptr = combb + ((size_t)kb*NNODE + m0 + c16)*NNODE + quad*8;  // [n][j]
    const ushort_t* Bbase = xtT + (size_t)kb*DIM*NNODE;                            // [d][j]
    int ncol0 = nblk*64;
    const ushort_t* Bptr0 = Bbase + (size_t)(ncol0 +  0 + c16)*NNODE + quad*8;
    const ushort_t* Bptr1 = Bbase + (size_t)(ncol0 + 16 + c16)*NNODE + quad*8;
    const ushort_t* Bptr2 = Bbase + (size_t)(ncol0 + 32 + c16)*NNODE + quad*8;
    const ushort_t* Bptr3 = Bbase + (size_t)(ncol0 + 48 + c16)*NNODE + quad*8;
    float4v acc0 = {0.f,0.f,0.f,0.f}, acc1 = acc0, acc2 = acc0, acc3 = acc0;
    #pragma unroll
    for (int ks=0; ks<2; ++ks){
        short8 a  = *reinterpret_cast<const short8*>(Aptr  + ks*32);
        short8 b0 = *reinterpret_cast<const short8*>(Bptr0 + ks*32);
        short8 b1v= *reinterpret_cast<const short8*>(Bptr1 + ks*32);
        short8 b2 = *reinterpret_cast<const short8*>(Bptr2 + ks*32);
        short8 b3 = *reinterpret_cast<const short8*>(Bptr3 + ks*32);
        acc0 = __builtin_amdgcn_mfma_f32_16x16x32_bf16(a, b0, acc0, 0,0,0);
        acc1 = __builtin_amdgcn_mfma_f32_16x16x32_bf16(a, b1v, acc1, 0,0,0);
        acc2 = __builtin_amdgcn_mfma_f32_16x16x32_bf16(a, b2, acc2, 0,0,0);
        acc3 = __builtin_amdgcn_mfma_f32_16x16x32_bf16(a, b3, acc3, 0,0,0);
    }
    size_t rowbase = (size_t)kb*NNODE;
    float4v accs[4] = {acc0, acc1, acc2, acc3};
    #pragma unroll
    for (int nt=0; nt<4; ++nt){
        int cg = ncol0 + nt*16 + c16;
        #pragma unroll
        for (int r=0;r<4;r++){
            int m = m0 + quad*4 + r;
            yb[(rowbase + m)*DIM + cg] = f2bu(accs[nt][r]);
        }
    }
}

// ---- MFMA gcn: [64 x 256] @ [256 x 256] + bias -> out_local f32 [b,k,d,n] ----
__global__ void __launch_bounds__(256) k_gcn_mfma(const ushort_t* __restrict__ yb,
                         const ushort_t* __restrict__ gwbt, const float* __restrict__ gb,
                         float* __restrict__ out_local)
{
    int blk = blockIdx.x;                 // 5*16*4
    int kband = blk / (BATCH*4);
    int b = (blk/4) % BATCH;
    int nblk = blk & 3;
    int tid = threadIdx.x;
    int wave = tid>>6, lane = tid&63;
    int c16 = lane & 15, quad = lane >> 4;
    int m0 = wave*16;
    int kb = kband*BATCH + b;
    const ushort_t* Aptr = yb + ((size_t)kb*NNODE + m0 + c16)*DIM + quad*8;  // [n][d]
    const ushort_t* Bbase = gwbt + (size_t)kband*DIM*DIM;                    // [col][kk]
    int ncol0 = nblk*64;
    const ushort_t* Bptr0 = Bbase + (size_t)(ncol0 +  0 + c16)*DIM + quad*8;
    const ushort_t* Bptr1 = Bbase + (size_t)(ncol0 + 16 + c16)*DIM + quad*8;
    const ushort_t* Bptr2 = Bbase + (size_t)(ncol0 + 32 + c16)*DIM + quad*8;
    const ushort_t* Bptr3 = Bbase + (size_t)(ncol0 + 48 + c16)*DIM + quad*8;
    float4v acc0 = {0.f,0.f,0.f,0.f}, acc1 = acc0, acc2 = acc0, acc3 = acc0;
    #pragma unroll
    for (int ks=0; ks<8; ++ks){
        short8 a  = *reinterpret_cast<const short8*>(Aptr  + ks*32);
        short8 b0 = *reinterpret_cast<const short8*>(Bptr0 + ks*32);
        short8 b1v= *reinterpret_cast<const short8*>(Bptr1 + ks*32);
        short8 b2 = *reinterpret_cast<const short8*>(Bptr2 + ks*32);
        short8 b3 = *reinterpret_cast<const short8*>(Bptr3 + ks*32);
        acc0 = __builtin_amdgcn_mfma_f32_16x16x32_bf16(a, b0, acc0, 0,0,0);
        acc1 = __builtin_amdgcn_mfma_f32_16x16x32_bf16(a, b1v, acc1, 0,0,0);
        acc2 = __builtin_amdgcn_mfma_f32_16x16x32_bf16(a, b2, acc2, 0,0,0);
        acc3 = __builtin_amdgcn_mfma_f32_16x16x32_bf16(a, b3, acc3, 0,0,0);
    }
    float4v accs[4] = {acc0, acc1, acc2, acc3};
    // transposed store: out_local[((b*5+kband)*256 + cg)*64 + n], n = m0+quad*4..+3 contiguous
    #pragma unroll
    for (int nt=0; nt<4; ++nt){
        int cg = ncol0 + nt*16 + c16;
        float bias = gb[kband*DIM + cg];
        float4 v = make_float4(accs[nt][0]+bias, accs[nt][1]+bias, accs[nt][2]+bias, accs[nt][3]+bias);
        float* dst = out_local + ((size_t)(b*NBANDS + kband)*DIM + cg)*NNODE + m0 + quad*4;
        *reinterpret_cast<float4*>(dst) = v;
    }
}

// ---------------- scale_nodes[b,k,d] = mean_n local_out[b,k,d,n] ------------
__global__ void k_scale(const float* __restrict__ out_local, float* __restrict__ scalew)
{
    int k = blockIdx.x / BATCH, b = blockIdx.x % BATCH;
    int d = threadIdx.x;
    const float4* zl = reinterpret_cast<const float4*>(out_local + ((size_t)(b*NBANDS + k)*DIM + d)*NNODE);
    float acc = 0.f;
    #pragma unroll
    for (int q=0;q<16;++q){
        float4 v = zl[q];
        acc += v.x + v.y + v.z + v.w;
    }
    scalew[((size_t)b*SEQ + k)*DIM + d] = acc * (1.f/64.f);
}

// ---- generic sliced GEMV: out[row][n] = act(bias[n] + sum_k x[row][k] w[k][n]) ----
template<int COLS, int SLICES>
__global__ void __launch_bounds__(256) k_gemv(const float* __restrict__ x, const float* __restrict__ w,
                       const float* __restrict__ bias, float* __restrict__ out,
                       int K, int N, int act)
{
    int chunks = N / COLS;
    int row = blockIdx.x / chunks;
    int n0 = (blockIdx.x % chunks) * COLS;
    int c = threadIdx.x % COLS, s = threadIdx.x / COLS;
    __shared__ float xs[1024];
    __shared__ float part[SLICES][COLS];
    for (int i = threadIdx.x; i < K; i += 256) xs[i] = x[(size_t)row*K + i];
    __syncthreads();
    int klen = K / SLICES;
    const float* wp = w + (size_t)(s*klen)*N + n0 + c;
    const float* xp = xs + s*klen;
    float acc = 0.f;
    #pragma unroll 8
    for (int i = 0; i < klen; ++i) acc += xp[i] * wp[(size_t)i*N];
    part[s][c] = acc;
    __syncthreads();
    if (s == 0){
        float v = bias[n0+c];
        #pragma unroll
        for (int q=0;q<SLICES;q++) v += part[q][c];
        if (act) v = 0.5f*v*(1.f + erff(v*0.70710678118654752f));
        out[(size_t)row*N + n0 + c] = v;
    }
}

// ---------------- MHA core: scores, softmax, att@v -> o_ws ------------------
__global__ void k_attn(const float* __restrict__ qkvw, float* __restrict__ ows)
{
    int b = blockIdx.x;
    int tid = threadIdx.x;
    int h = tid >> 6, l = tid & 63;
    __shared__ float att[NHEAD][SEQ][SEQ];
    const float* base = qkvw + (size_t)b*SEQ*3*DIM;
    for (int i=0;i<SEQ;i++){
        float qv = base[(size_t)i*3*DIM + h*DHEAD + l];
        for (int j=0;j<SEQ;j++){
            float kv = base[(size_t)j*3*DIM + DIM + h*DHEAD + l];
            float p = qv * kv;
            for (int o=32;o>0;o>>=1) p += __shfl_xor(p,o,64);
            if (l==0) att[h][i][j] = p * 0.125f;
        }
    }
    __syncthreads();
    if (l == 0){
        for (int i=0;i<SEQ;i++){
            float m=-1e30f;
            for (int j=0;j<SEQ;j++) m = fmaxf(m, att[h][i][j]);
            float e[SEQ]; float s=0.f;
            for (int j=0;j<SEQ;j++){ e[j] = __expf(att[h][i][j]-m); s+=e[j]; }
            for (int j=0;j<SEQ;j++) att[h][i][j] = e[j]/s;
        }
    }
    __syncthreads();
    for (int i=0;i<SEQ;i++){
        float acc=0.f;
        for (int j=0;j<SEQ;j++) acc += att[h][i][j] * base[(size_t)j*3*DIM + 2*DIM + h*DHEAD + l];
        ows[((size_t)b*SEQ + i)*DIM + h*DHEAD + l] = acc;
    }
}

// ---------------- block LayerNorm over 256 elems ----------------------------
__device__ __forceinline__ float block_ln(float v, int tid, float* red, float g, float bln)
{
    float s = v;
    for (int o=32;o>0;o>>=1) s += __shfl_xor(s,o,64);
    int wave = tid>>6, lane = tid&63;
    if (lane==0) red[wave] = s;
    __syncthreads();
    float mean = (red[0]+red[1]+red[2]+red[3]) * (1.f/DIM);
    float c = v - mean;
    float q = c*c;
    for (int o=32;o>0;o>>=1) q += __shfl_xor(q,o,64);
    __syncthreads();
    if (lane==0) red[wave] = q;
    __syncthreads();
    float var = (red[0]+red[1]+red[2]+red[3]) * (1.f/DIM);
    return c * rsqrtf(var + 1e-5f) * g + bln;
}

// ---------------- residual + LN: out = LN(a+r)*g + be -----------------------
__global__ void k_ln(const float* __restrict__ a, const float* __restrict__ r,
                     const float* __restrict__ g, const float* __restrict__ be,
                     float* __restrict__ out)
{
    int row = blockIdx.x;
    int d = threadIdx.x;
    __shared__ float red[4];
    float v = a[(size_t)row*DIM + d] + r[(size_t)row*DIM + d];
    out[(size_t)row*DIM + d] = block_ln(v, d, red, g[d], be[d]);
}

// ---------------- global adj: dyn, comb softmax -> gcomb ws + f32 out -------
__global__ void k_gadj(const float* __restrict__ gaw, const float* __restrict__ gbw,
                       const float* __restrict__ gw2, const float* __restrict__ gb2,
                       const float* __restrict__ gbase,
                       float* __restrict__ gcombw, float* __restrict__ out_gadj)
{
    int b = blockIdx.x;
    int tid = threadIdx.x;
    int wave = tid>>6, lane = tid&63;
    __shared__ float dyn[SEQ][SEQ];
    __shared__ float w2s[DIM];
    w2s[tid] = gw2[tid];
    __syncthreads();
    for (int p = wave; p < SEQ*SEQ; p += 4){
        int i = p / SEQ, j = p % SEQ;
        const float* gar = gaw + ((size_t)b*SEQ+i)*DIM;
        const float* gbr = gbw + ((size_t)b*SEQ+j)*DIM;
        float acc = 0.f;
        #pragma unroll
        for (int m=0;m<4;m++){
            int dd = lane + m*64;
            float v = gar[dd] + gbr[dd];
            float e = (v>0.f) ? v : (__expf(v)-1.f);
            acc += e * w2s[dd];
        }
        for (int o=32;o>0;o>>=1) acc += __shfl_xor(acc,o,64);
        if (lane==0) dyn[i][j] = acc;
    }
    __syncthreads();
    if (tid < SEQ){
        int i = tid;
        float sb2 = gb2[0];
        float row[SEQ]; float m=-1e30f;
        for (int j=0;j<SEQ;j++){
            float sg = 1.f/(1.f+__expf(-(dyn[i][j]+sb2)));
            row[j] = gbase[i*SEQ+j] + sg;
            m = fmaxf(m,row[j]);
        }
        float ssum=0.f;
        for (int j=0;j<SEQ;j++){ row[j]=__expf(row[j]-m); ssum+=row[j]; }
        for (int j=0;j<SEQ;j++){
            float c = row[j]/ssum;
            gcombw[((size_t)b*SEQ+i)*SEQ + j] = c;
            out_gadj[((size_t)b*SEQ+i)*SEQ + j] = c;
        }
    }
}

// ---------------- trow[row][d] = sum_j gcomb[row][j]*se[b,j,d] --------------
__global__ void k_gmix(const float* __restrict__ gcombw, const float* __restrict__ sew,
                       float* __restrict__ trow)
{
    int row = blockIdx.x;          // b*SEQ+k
    int b = row / SEQ;
    int d = threadIdx.x;
    float t = 0.f;
    #pragma unroll
    for (int j=0;j<SEQ;j++) t += gcombw[row*SEQ + j] * sew[((size_t)b*SEQ + j)*DIM + d];
    trow[(size_t)row*DIM + d] = t;
}

// ------- final: out0[b,k,d] = gout[b,k,d] * (sum_n local_out*imp_w) + imp_b --
__global__ void k_final(const float* __restrict__ out_local,
                        const float* __restrict__ goutw,
                        const float* __restrict__ imp_w, const float* __restrict__ imp_b,
                        float* __restrict__ out0)
{
    int b = blockIdx.x / NBANDS, k = blockIdx.x % NBANDS;
    __shared__ float iw[NNODE];
    int d = threadIdx.x;
    if (d < NNODE) iw[d] = imp_w[k*NNODE + d];
    __syncthreads();
    const float4* zl = reinterpret_cast<const float4*>(out_local + ((size_t)(b*NBANDS + k)*DIM + d)*NNODE);
    float acc = 0.f;
    #pragma unroll
    for (int q=0;q<16;++q){
        float4 v = zl[q];
        acc += v.x*iw[q*4] + v.y*iw[q*4+1] + v.z*iw[q*4+2] + v.w*iw[q*4+3];
    }
    float val = goutw[((size_t)b*NBANDS+k)*DIM + d] * acc + imp_b[k];
    out0[((size_t)b*NBANDS+k)*DIM + d] = val;
}

extern "C" void kernel_launch(void* const* d_in, const int* in_sizes, int n_in,
                              void* d_out, int out_size, void* d_ws, size_t ws_size,
                              hipStream_t stream)
{
    const float* feature      = (const float*)d_in[0];
    const float* l_adj_w      = (const float*)d_in[1];
    const float* l_sim_w1     = (const float*)d_in[2];
    const float* l_sim_b1     = (const float*)d_in[3];
    const float* l_sim_w2     = (const float*)d_in[4];
    const float* l_sim_b2     = (const float*)d_in[5];
    const float* l_pos_factor = (const float*)d_in[6];
    const float* l_pos_enc    = (const float*)d_in[7];
    const float* l_gcn_w      = (const float*)d_in[8];
    const float* l_gcn_b      = (const float*)d_in[9];
    const float* g_adj_w      = (const float*)d_in[10];
    const float* g_sim_w1     = (const float*)d_in[11];
    const float* g_sim_b1     = (const float*)d_in[12];
    const float* g_sim_w2     = (const float*)d_in[13];
    const float* g_sim_b2     = (const float*)d_in[14];
    const float* g_pos_factor = (const float*)d_in[15];
    const float* g_pos_enc    = (const float*)d_in[16];
    const float* g_gcn_w      = (const float*)d_in[17];
    const float* g_gcn_b      = (const float*)d_in[18];
    const float* qkv_w        = (const float*)d_in[19];
    const float* qkv_b        = (const float*)d_in[20];
    const float* attn_ow      = (const float*)d_in[21];
    const float* attn_ob      = (const float*)d_in[22];
    const float* ln1_g        = (const float*)d_in[23];
    const float* ln1_b        = (const float*)d_in[24];
    const float* ln2_g        = (const float*)d_in[25];
    const float* ln2_b        = (const float*)d_in[26];
    const float* mlp_w1       = (const float*)d_in[27];
    const float* mlp_b1       = (const float*)d_in[28];
    const float* mlp_w2       = (const float*)d_in[29];
    const float* mlp_b2       = (const float*)d_in[30];
    const float* imp_w        = (const float*)d_in[31];
    const float* imp_b        = (const float*)d_in[32];

    float* out0      = (float*)d_out;
    float* out_gadj  = out0 + (size_t)BATCH*NBANDS*DIM;
    float* out_local = out_gadj + (size_t)BATCH*NBANDS*NBANDS;

    const size_t BIG = (size_t)NBANDS*BATCH*NNODE*DIM;           // 1,310,720 elems
    ushort_t* xtb   = (ushort_t*)d_ws;                           // bf16 [k,b,n,d]
    ushort_t* aab   = xtb + BIG;                                 // bf16 a (reused as y)
    ushort_t* bbb   = aab + BIG;                                 // bf16 bp
    ushort_t* xtT   = bbb + BIG;                                 // bf16 [k,b,d,n]
    ushort_t* yb    = aab;
    ushort_t* w1bt  = xtT + BIG;                                 // bf16 [k][512][256]
    ushort_t* gwbt  = w1bt + (size_t)NBANDS*512*DIM;             // bf16 [k][256][256]
    ushort_t* combb = gwbt + (size_t)NBANDS*DIM*DIM;             // bf16 [kb][64][64]
    float* fp = (float*)(combb + (size_t)NBANDS*BATCH*NNODE*NNODE);
    float* sbase  = fp; fp += NBANDS*NNODE*NNODE;
    float* gbase  = fp; fp += 32;
    float* zbuf   = fp; fp += DIM;
    float* scalew = fp; fp += BATCH*SEQ*DIM;
    float* qkvw   = fp; fp += BATCH*SEQ*3*DIM;
    float* ows    = fp; fp += BATCH*SEQ*DIM;
    float* projw  = fp; fp += BATCH*SEQ*DIM;
    float* h1w    = fp; fp += BATCH*SEQ*DIM;
    float* mhw    = fp; fp += BATCH*SEQ*4*DIM;
    float* m2w    = fp; fp += BATCH*SEQ*DIM;
    float* sew    = fp; fp += BATCH*SEQ*DIM;
    float* gaw    = fp; fp += BATCH*SEQ*DIM;
    float* gbw    = fp; fp += BATCH*SEQ*DIM;
    float* gcombw = fp; fp += 512;
    float* trow   = fp; fp += BATCH*SEQ*DIM;
    float* goutw  = fp; fp += BATCH*SEQ*DIM;

    const int ROWS = BATCH*SEQ;   // 80

    k_bases<<<NBANDS*NNODE + 2, 64, 0, stream>>>(l_adj_w, l_pos_enc, l_pos_factor,
                                                 g_adj_w, g_pos_enc, g_pos_factor,
                                                 sbase, gbase, zbuf);
    k_prep<<<240, 256, 0, stream>>>(l_sim_w1, l_gcn_w, w1bt, gwbt);
    k_transpose_feat<<<NBANDS*BATCH, 256, 0, stream>>>(feature, xtb, xtT);
    k_ab_mfma<<<NBANDS*BATCH*8, 256, 0, stream>>>(xtb, w1bt, l_sim_b1, aab, bbb);
    k_dyn_comb<<<NBANDS*BATCH*16, 256, 0, stream>>>(aab, bbb, l_sim_w2, l_sim_b2, sbase, combb);
    k_y_mfma<<<NBANDS*BATCH*4, 256, 0, stream>>>(combb, xtT, yb);
    k_gcn_mfma<<<NBANDS*BATCH*4, 256, 0, stream>>>(yb, gwbt, l_gcn_b, out_local);
    k_scale<<<NBANDS*BATCH, 256, 0, stream>>>(out_local, scalew);
    k_gemv<64,4><<<ROWS*12, 256, 0, stream>>>(scalew, qkv_w, qkv_b, qkvw, 256, 768, 0);
    k_attn<<<BATCH, 256, 0, stream>>>(qkvw, ows);
    k_gemv<64,4><<<ROWS*4, 256, 0, stream>>>(ows, attn_ow, attn_ob, projw, 256, 256, 0);
    k_ln<<<ROWS, 256, 0, stream>>>(projw, scalew, ln1_g, ln1_b, h1w);
    k_gemv<64,4><<<ROWS*16, 256, 0, stream>>>(h1w, mlp_w1, mlp_b1, mhw, 256, 1024, 1);
    k_gemv<32,8><<<ROWS*8, 256, 0, stream>>>(mhw, mlp_w2, mlp_b2, m2w, 1024, 256, 0);
    k_ln<<<ROWS, 256, 0, stream>>>(m2w, h1w, ln2_g, ln2_b, sew);
    k_gemv<64,4><<<ROWS*4, 256, 0, stream>>>(sew, g_sim_w1, g_sim_b1, gaw, 256, 256, 0);
    k_gemv<64,4><<<ROWS*4, 256, 0, stream>>>(sew, g_sim_w1 + (size_t)DIM*DIM, zbuf, gbw, 256, 256, 0);
    k_gadj<<<BATCH, 256, 0, stream>>>(gaw, gbw, g_sim_w2, g_sim_b2, gbase, gcombw, out_gadj);
    k_gmix<<<ROWS, 256, 0, stream>>>(gcombw, sew, trow);
    k_gemv<64,4><<<ROWS*4, 256, 0, stream>>>(trow, g_gcn_w, g_gcn_b, goutw, 256, 256, 0);
    k_final<<<BATCH*NBANDS, 256, 0, stream>>>(out_local, goutw, imp_w, imp_b, out0);
}